// Round 6
// baseline (481.900 us; speedup 1.0000x reference)
//
#include <hip/hip_runtime.h>
#include <hip/hip_bf16.h>

#define B_   32
#define N_   4096
#define D_   768
#define HID_ 256

#define SX 64.0f
#define SW 1024.0f
#define INV_S (1.0f / 65536.0f)

typedef unsigned long long ull;
typedef _Float16 half8 __attribute__((ext_vector_type(8)));
typedef float f32x16 __attribute__((ext_vector_type(16)));

#define LGKM0_BARRIER() do { \
    asm volatile("s_waitcnt lgkmcnt(0)" ::: "memory"); \
    __builtin_amdgcn_s_barrier(); \
  } while (0)

// ---------------- Kernel P: fused prep: W-split (blocks 0..95) + label proj (96..127) --
// Whi/Wlo layout: [96 chunks][256 hid][8 k] f16, chunk c covers k = c*8..c*8+7.
// This IS the 32x32x16 A-fragment order: lane reads 16B at (c*256+hid)*8.
__global__ __launch_bounds__(256) void prep_kernel(
    const float* __restrict__ W1, _Float16* __restrict__ whi,
    _Float16* __restrict__ wlo, const float* __restrict__ lc,
    const float* __restrict__ Wp, const float* __restrict__ bp,
    float* __restrict__ lbl_n) {
  if (blockIdx.x < 96) {
    int c = blockIdx.x;
    int h = threadIdx.x;
    half8 vh, vl;
#pragma unroll
    for (int j = 0; j < 8; ++j) {
      float w = W1[(size_t)(c * 8 + j) * 256 + h] * SW;
      _Float16 hi = (_Float16)w;
      vh[j] = hi;
      vl[j] = (_Float16)(w - (float)hi);
    }
    *(half8*)&whi[((size_t)c * 256 + h) * 8] = vh;
    *(half8*)&wlo[((size_t)c * 256 + h) * 8] = vl;
    return;
  }
  // label projection + L2 normalize
  int b = blockIdx.x - 96;
  int t = threadIdx.x;
  __shared__ float s_lc[128];
  __shared__ float s_out[768];
  __shared__ float s_red[4];

  if (t < 128) s_lc[t] = lc[b * 128 + t];
  __syncthreads();

  float sumsq = 0.f;
  for (int d = t; d < D_; d += 256) {
    float acc = bp[d];
    for (int k = 0; k < 128; ++k) acc += s_lc[k] * Wp[k * D_ + d];
    s_out[d] = acc;
    sumsq += acc * acc;
  }
  for (int off = 32; off >= 1; off >>= 1) sumsq += __shfl_xor(sumsq, off);
  if ((t & 63) == 0) s_red[t >> 6] = sumsq;
  __syncthreads();
  float tot = s_red[0] + s_red[1] + s_red[2] + s_red[3];
  float inv = 1.f / fmaxf(sqrtf(tot), 1e-12f);
  for (int d = t; d < D_; d += 256) lbl_n[b * D_ + d] = s_out[d] * inv;
}

// ---------------- Kernel B: split-f16 MFMA score kernel, v7 ----------------
// Block: 8 waves (512 thr) = 256 patches x 256 hid. Wave (hh=w>>2, pg=w&3):
// hidden half hh*128 (mt=4 A-tiles), patches pg*64 (bt=2 B-tiles); acc 8 x f32x16.
// W A-frags: DIRECT from global (L2-resident, frag-ordered), depth-1 reg prefetch.
// X: split to f16 hi/lo on the staging path, 32KB LDS dbuf, depth-2 reg prefetch.
// One lgkmcnt(0)+s_barrier per K16 stage. launch_bounds(512,1): no spills.
__global__ __launch_bounds__(512, 1) void score7_kernel(
    const float* __restrict__ X, const _Float16* __restrict__ Whi,
    const _Float16* __restrict__ Wlo, const float* __restrict__ b1,
    const float* __restrict__ W2, const float* __restrict__ b2,
    const float* __restrict__ lbl_n, float* __restrict__ scores) {
  __shared__ __align__(16) _Float16 sB[2][2][2][256][8];  // [buf][hl][k8][patch][8] 32KB
  __shared__ __align__(16) float sLbl[768];
  __shared__ float sB1[256], sW2[256];
  __shared__ float sVs[2][256];
  __shared__ float sLsc[256];

  const int t  = threadIdx.x;
  const int w  = t >> 6;
  const int l  = t & 63;
  const int l5 = l >> 5;
  const int ln = l & 31;
  const int hh = w >> 2;
  const int pg = w & 3;
  const int pb = blockIdx.x * 256;
  const int batch = pb >> 12;

  for (int i = t; i < D_; i += 512) sLbl[i] = lbl_n[batch * D_ + i];
  if (t < 256) { sB1[t] = b1[t]; sW2[t] = W2[t]; }

  // staging role: thread t owns patch row r = t>>1, k8-half h2 = t&1
  const int r  = t >> 1;
  const int h2 = t & 1;
  const float* xrow = X + (size_t)(pb + r) * D_ + h2 * 8;

  const half8* gWh = (const half8*)Whi;
  const half8* gWl = (const half8*)Wlo;
  const int hidb = hh * 128 + ln;  // + mt*32

  f32x16 acc[4][2];
#pragma unroll
  for (int mt = 0; mt < 4; ++mt)
#pragma unroll
    for (int bt = 0; bt < 2; ++bt)
#pragma unroll
      for (int q = 0; q < 16; ++q) acc[mt][bt][q] = 0.f;

  float sq = 0.f, dt = 0.f;

  // ---- prologue ----
  float4 x00 = *(const float4*)(xrow + 0);
  float4 x01 = *(const float4*)(xrow + 4);
  half8 ah[4], al[4], ph[4], pl[4];
#pragma unroll
  for (int mt = 0; mt < 4; ++mt) {
    ah[mt] = gWh[l5 * 256 + hidb + mt * 32];   // chunk c = 2*0 + l5
    al[mt] = gWl[l5 * 256 + hidb + mt * 32];
  }
  __syncthreads();  // sLbl/sB1/sW2 ready

  {  // split X(0) + stats -> sB[0]
    half8 bh_, bl_;
#pragma unroll
    for (int j = 0; j < 8; ++j) {
      float xv = (j < 4) ? (&x00.x)[j] : (&x01.x)[j - 4];
      float lv = sLbl[h2 * 8 + j];
      sq += xv * xv;
      dt += xv * lv;
      float xs = xv * SX;
      _Float16 hi = (_Float16)xs;
      bh_[j] = hi;
      bl_[j] = (_Float16)(xs - (float)hi);
    }
    *(half8*)&sB[0][0][h2][r][0] = bh_;
    *(half8*)&sB[0][1][h2][r][0] = bl_;
  }
  float4 xa0 = *(const float4*)(xrow + 16);       // X(1)
  float4 xa1 = *(const float4*)(xrow + 20);
  float4 xb0 = *(const float4*)(xrow + 32);       // X(2)
  float4 xb1 = *(const float4*)(xrow + 36);
  LGKM0_BARRIER();

  // ---- main loop: 48 K16 stages; X reg sets ping-pong (xa even, xb odd) ----
#define STAGE_BODY(S, XW0, XW1)                                                \
  {                                                                            \
    const int c = (S) & 1;                                                     \
    /* W(S+1) frag prefetch */                                                 \
    if ((S) < 47) {                                                            \
      const int cc = ((S) + 1) * 2 + l5;                                       \
      _Pragma("unroll")                                                        \
      for (int mt = 0; mt < 4; ++mt) {                                         \
        ph[mt] = gWh[cc * 256 + hidb + mt * 32];                               \
        pl[mt] = gWl[cc * 256 + hidb + mt * 32];                               \
      }                                                                        \
    }                                                                          \
    /* X(S+3) into fresh regs (consumed 2 stages later) */                     \
    float4 nx0, nx1;                                                           \
    {                                                                          \
      const int s3 = ((S) + 3 > 47) ? 47 : (S) + 3;                            \
      nx0 = *(const float4*)(xrow + s3 * 16);                                  \
      nx1 = *(const float4*)(xrow + s3 * 16 + 4);                              \
    }                                                                          \
    /* B-frags + MFMA cluster */                                               \
    {                                                                          \
      half8 bh[2], bl[2];                                                      \
      _Pragma("unroll")                                                        \
      for (int bt = 0; bt < 2; ++bt) {                                         \
        bh[bt] = *(const half8*)&sB[c][0][l5][pg * 64 + bt * 32 + ln][0];      \
        bl[bt] = *(const half8*)&sB[c][1][l5][pg * 64 + bt * 32 + ln][0];      \
      }                                                                        \
      __builtin_amdgcn_s_setprio(1);                                           \
      _Pragma("unroll")                                                        \
      for (int mt = 0; mt < 4; ++mt)                                           \
        _Pragma("unroll")                                                      \
        for (int bt = 0; bt < 2; ++bt)                                         \
          acc[mt][bt] = __builtin_amdgcn_mfma_f32_32x32x16_f16(                \
              ah[mt], bh[bt], acc[mt][bt], 0, 0, 0);                           \
      _Pragma("unroll")                                                        \
      for (int mt = 0; mt < 4; ++mt)                                           \
        _Pragma("unroll")                                                      \
        for (int bt = 0; bt < 2; ++bt)                                         \
          acc[mt][bt] = __builtin_amdgcn_mfma_f32_32x32x16_f16(                \
              ah[mt], bl[bt], acc[mt][bt], 0, 0, 0);                           \
      _Pragma("unroll")                                                        \
      for (int mt = 0; mt < 4; ++mt)                                           \
        _Pragma("unroll")                                                      \
        for (int bt = 0; bt < 2; ++bt)                                         \
          acc[mt][bt] = __builtin_amdgcn_mfma_f32_32x32x16_f16(                \
              al[mt], bh[bt], acc[mt][bt], 0, 0, 0);                           \
      __builtin_amdgcn_s_setprio(0);                                           \
    }                                                                          \
    /* split X(S+1) + stats -> sB[c^1] */                                      \
    if ((S) < 47) {                                                            \
      half8 nbh, nbl;                                                          \
      _Pragma("unroll")                                                        \
      for (int j = 0; j < 8; ++j) {                                            \
        float xv = (j < 4) ? (&XW0.x)[j] : (&XW1.x)[j - 4];                    \
        float lv = sLbl[((S) + 1) * 16 + h2 * 8 + j];                          \
        sq += xv * xv;                                                         \
        dt += xv * lv;                                                         \
        float xs = xv * SX;                                                    \
        _Float16 hi = (_Float16)xs;                                            \
        nbh[j] = hi;                                                           \
        nbl[j] = (_Float16)(xs - (float)hi);                                   \
      }                                                                        \
      *(half8*)&sB[c ^ 1][0][h2][r][0] = nbh;                                  \
      *(half8*)&sB[c ^ 1][1][h2][r][0] = nbl;                                  \
      _Pragma("unroll")                                                        \
      for (int mt = 0; mt < 4; ++mt) { ah[mt] = ph[mt]; al[mt] = pl[mt]; }     \
    }                                                                          \
    XW0 = nx0; XW1 = nx1;                                                      \
    LGKM0_BARRIER();                                                           \
  }

  for (int ss = 0; ss < 24; ++ss) {
    STAGE_BODY(2 * ss,     xa0, xa1)
    STAGE_BODY(2 * ss + 1, xb0, xb1)
  }
#undef STAGE_BODY

  // ---- epilogue ----
  sq += __shfl_xor(sq, 1);
  dt += __shfl_xor(dt, 1);
  if (h2 == 0) sLsc[r] = dt / fmaxf(sqrtf(sq), 1e-12f);

  float vsb[2] = {0.f, 0.f};
#pragma unroll
  for (int mt = 0; mt < 4; ++mt) {
#pragma unroll
    for (int rq = 0; rq < 4; ++rq) {
      const int hb = hh * 128 + mt * 32 + rq * 8 + l5 * 4;
      const float4 b1v = *(const float4*)&sB1[hb];
      const float4 w2v = *(const float4*)&sW2[hb];
#pragma unroll
      for (int j = 0; j < 4; ++j) {
        float h0 = acc[mt][0][rq * 4 + j] * INV_S + (&b1v.x)[j];
        float h1 = acc[mt][1][rq * 4 + j] * INV_S + (&b1v.x)[j];
        vsb[0] += fmaxf(h0, 0.f) * (&w2v.x)[j];
        vsb[1] += fmaxf(h1, 0.f) * (&w2v.x)[j];
      }
    }
  }
  vsb[0] += __shfl_xor(vsb[0], 32);
  vsb[1] += __shfl_xor(vsb[1], 32);
  if (l < 32) {
    sVs[hh][pg * 64 + l]      = vsb[0];
    sVs[hh][pg * 64 + 32 + l] = vsb[1];
  }
  __syncthreads();

  if (t < 256) {
    float vst = sVs[0][t] + sVs[1][t] + b2[0];
    scores[pb + t] = 0.4f * vst + 0.6f * sLsc[t];
  }
}

// ---------------- Kernel C: per-batch exact top-K (descending, tie->lower idx) --
__global__ __launch_bounds__(256) void topk2_kernel(
    const float* __restrict__ scores, int* __restrict__ out_idx, int K) {
  int b = blockIdx.x;
  int t = threadIdx.x;
  __shared__ ull swm[4];

  ull keys[16];
#pragma unroll
  for (int j = 0; j < 16; ++j) {
    int i = (j << 8) + t;  // coalesced
    float s = scores[(b << 12) + i];
    unsigned u = __float_as_uint(s);
    u = (u & 0x80000000u) ? ~u : (u | 0x80000000u);
    keys[j] = ((ull)u << 32) | (unsigned)(4095 - i);  // tie -> lower index wins
  }
  ull cur = 0;
#pragma unroll
  for (int j = 0; j < 16; ++j) cur = keys[j] > cur ? keys[j] : cur;

  for (int sel = 0; sel < K; ++sel) {
    ull wb = cur;
#pragma unroll
    for (int off = 1; off < 64; off <<= 1) {
      ull o = __shfl_xor(wb, off);
      wb = o > wb ? o : wb;
    }
    if ((t & 63) == 0) swm[t >> 6] = wb;
    __syncthreads();
    ull m0 = swm[0] > swm[1] ? swm[0] : swm[1];
    ull m1 = swm[2] > swm[3] ? swm[2] : swm[3];
    ull best = m0 > m1 ? m0 : m1;
    if (t == 0) out_idx[b * K + sel] = 4095 - (int)(unsigned)(best & 0xFFFFFFFFull);
    if (cur == best) {
      cur = 0;
#pragma unroll
      for (int j = 0; j < 16; ++j)
        cur = (keys[j] < best && keys[j] > cur) ? keys[j] : cur;
    }
    __syncthreads();
  }
}

// ---------------- Kernel D: gather + float-encode indices ----------------
__global__ __launch_bounds__(192) void gather_kernel(
    const float* __restrict__ feats, const int* __restrict__ idx,
    float* __restrict__ out_feats, float* __restrict__ out_idx_f, int K) {
  int i = blockIdx.x;
  int b = blockIdx.y;
  int id = idx[b * K + i];
  const float4* src = (const float4*)&feats[((size_t)b * N_ + id) * D_];
  float4* dst = (float4*)&out_feats[((size_t)b * K + i) * D_];
  dst[threadIdx.x] = src[threadIdx.x];
  if (threadIdx.x == 0) out_idx_f[b * K + i] = (float)id;
}

extern "C" void kernel_launch(void* const* d_in, const int* in_sizes, int n_in,
                              void* d_out, int out_size, void* d_ws, size_t ws_size,
                              hipStream_t stream) {
  const float* feats = (const float*)d_in[0];
  const float* lc    = (const float*)d_in[1];
  const float* W1    = (const float*)d_in[2];
  const float* b1    = (const float*)d_in[3];
  const float* W2    = (const float*)d_in[4];
  const float* b2    = (const float*)d_in[5];
  const float* Wp    = (const float*)d_in[6];
  const float* bp    = (const float*)d_in[7];
  int K = out_size / (B_ * (D_ + 1));  // 192

  float* ws_f    = (float*)d_ws;
  float* lbl_n   = ws_f;                              // 32*768
  float* scoresv = ws_f + B_ * D_;                    // 32*4096
  int*   topidx  = (int*)(ws_f + B_ * D_ + B_ * N_);  // 32*192
  size_t off = (size_t)B_ * D_ + (size_t)B_ * N_ + B_ * 256;
  off = (off + 3) & ~(size_t)3;
  _Float16* whi = (_Float16*)(ws_f + off);            // 96*256*8 halves
  _Float16* wlo = whi + (size_t)96 * 256 * 8;

  float* out_f     = (float*)d_out;
  float* out_idx_f = out_f + (size_t)B_ * K * D_;

  prep_kernel<<<128, 256, 0, stream>>>(W1, whi, wlo, lc, Wp, bp, lbl_n);
  score7_kernel<<<(B_ * N_) / 256, 512, 0, stream>>>(feats, whi, wlo, b1, W2, b2,
                                                     lbl_n, scoresv);
  topk2_kernel<<<B_, 256, 0, stream>>>(scoresv, topidx, K);
  gather_kernel<<<dim3(K, B_), 192, 0, stream>>>(feats, topidx, out_f, out_idx_f, K);
}

// Round 7
// 358.401 us; speedup vs baseline: 1.3446x; 1.3446x over previous
//
#include <hip/hip_runtime.h>
#include <hip/hip_bf16.h>

#define B_   32
#define N_   4096
#define D_   768
#define HID_ 256

#define SX 64.0f
#define SW 1024.0f
#define INV_S (1.0f / 65536.0f)

typedef unsigned long long ull;
typedef _Float16 half8 __attribute__((ext_vector_type(8)));
typedef float f32x16 __attribute__((ext_vector_type(16)));

#define LGKM0_BARRIER() do { \
    asm volatile("s_waitcnt lgkmcnt(0)" ::: "memory"); \
    __builtin_amdgcn_s_barrier(); \
  } while (0)

// ---------------- Kernel P: fused prep: W-split (blocks 0..95) + label proj (96..127)
// Whi/Wlo layout: [96 chunks][256 hid][8 k] f16, chunk c covers k = c*8..c*8+7.
// This IS the 32x32x16 A-fragment order: lane reads 16B at (c*256+hid)*8.
__global__ __launch_bounds__(256) void prep_kernel(
    const float* __restrict__ W1, _Float16* __restrict__ whi,
    _Float16* __restrict__ wlo, const float* __restrict__ lc,
    const float* __restrict__ Wp, const float* __restrict__ bp,
    float* __restrict__ lbl_n) {
  if (blockIdx.x < 96) {
    int c = blockIdx.x;
    int h = threadIdx.x;
    half8 vh, vl;
#pragma unroll
    for (int j = 0; j < 8; ++j) {
      float w = W1[(size_t)(c * 8 + j) * 256 + h] * SW;
      _Float16 hi = (_Float16)w;
      vh[j] = hi;
      vl[j] = (_Float16)(w - (float)hi);
    }
    *(half8*)&whi[((size_t)c * 256 + h) * 8] = vh;
    *(half8*)&wlo[((size_t)c * 256 + h) * 8] = vl;
    return;
  }
  int b = blockIdx.x - 96;
  int t = threadIdx.x;
  __shared__ float s_lc[128];
  __shared__ float s_out[768];
  __shared__ float s_red[4];

  if (t < 128) s_lc[t] = lc[b * 128 + t];
  __syncthreads();

  float sumsq = 0.f;
  for (int d = t; d < D_; d += 256) {
    float acc = bp[d];
    for (int k = 0; k < 128; ++k) acc += s_lc[k] * Wp[k * D_ + d];
    s_out[d] = acc;
    sumsq += acc * acc;
  }
  for (int off = 32; off >= 1; off >>= 1) sumsq += __shfl_xor(sumsq, off);
  if ((t & 63) == 0) s_red[t >> 6] = sumsq;
  __syncthreads();
  float tot = s_red[0] + s_red[1] + s_red[2] + s_red[3];
  float inv = 1.f / fmaxf(sqrtf(tot), 1e-12f);
  for (int d = t; d < D_; d += 256) lbl_n[b * D_ + d] = s_out[d] * inv;
}

// ---------------- Kernel B: split-f16 MFMA score kernel, v8 ----------------
// Block: 4 waves (256 thr) = 128 patches x 256 hid. Wave (hh=w>>1, pg=w&1):
// hidden half hh*128 (mt=4 A-tiles), patches pg*64 (bt=2 B-tiles); acc 8 x f32x16.
// W A-frags DIRECT from L2 (frag-ordered), explicit ping-pong reg sets A/B (no copy).
// X: f16 hi/lo split on staging path, 16KB LDS dbuf, depth-2 in-place reg reload.
// Exactly one lgkmcnt(0)+s_barrier per K16 stage; vmcnt stays counted.
__global__ __launch_bounds__(256, 2) void score8_kernel(
    const float* __restrict__ X, const _Float16* __restrict__ Whi,
    const _Float16* __restrict__ Wlo, const float* __restrict__ b1,
    const float* __restrict__ W2, const float* __restrict__ b2,
    const float* __restrict__ lbl_n, float* __restrict__ scores) {
  __shared__ __align__(16) _Float16 sB[2][2][2][128][8];  // [buf][hl][k8][row][8] 16KB
  __shared__ __align__(16) float sLbl[768];
  __shared__ float sB1[256], sW2[256];
  __shared__ float sVs[2][128];
  __shared__ float sLsc[128];

  const int t  = threadIdx.x;
  const int w  = t >> 6;
  const int l  = t & 63;
  const int l5 = l >> 5;
  const int ln = l & 31;
  const int hh = w >> 1;
  const int pg = w & 1;
  const int pb = blockIdx.x * 128;
  const int batch = pb >> 12;

  for (int i = t; i < D_; i += 256) sLbl[i] = lbl_n[batch * D_ + i];
  sB1[t] = b1[t];
  sW2[t] = W2[t];

  // staging role: thread t owns patch row r, k8-half h2
  const int r  = t >> 1;
  const int h2 = t & 1;
  const float* xrow = X + (size_t)(pb + r) * D_ + h2 * 8;

  const half8* gWh = (const half8*)Whi;
  const half8* gWl = (const half8*)Wlo;
  const int hidb = hh * 128 + ln;  // + mt*32

  f32x16 acc[4][2];
#pragma unroll
  for (int mt = 0; mt < 4; ++mt)
#pragma unroll
    for (int bt = 0; bt < 2; ++bt)
#pragma unroll
      for (int q = 0; q < 16; ++q) acc[mt][bt][q] = 0.f;

  float sq = 0.f, dt = 0.f;

  // split+store helper (also accumulates label stats)
#define SPLIT_STORE(BUF, V0, V1, SIDX)                                         \
  {                                                                            \
    half8 nbh, nbl;                                                            \
    _Pragma("unroll")                                                          \
    for (int j = 0; j < 8; ++j) {                                              \
      float xv = (j < 4) ? (&(V0).x)[j] : (&(V1).x)[j - 4];                    \
      float lv = sLbl[(SIDX) * 16 + h2 * 8 + j];                               \
      sq += xv * xv;                                                           \
      dt += xv * lv;                                                           \
      float xs = xv * SX;                                                      \
      _Float16 hi = (_Float16)xs;                                              \
      nbh[j] = hi;                                                             \
      nbl[j] = (_Float16)(xs - (float)hi);                                     \
    }                                                                          \
    *(half8*)&sB[BUF][0][h2][r][0] = nbh;                                      \
    *(half8*)&sB[BUF][1][h2][r][0] = nbl;                                      \
  }

#define MFMA_CLUSTER(AH, AL)                                                   \
  {                                                                            \
    __builtin_amdgcn_s_setprio(1);                                             \
    _Pragma("unroll")                                                          \
    for (int mt = 0; mt < 4; ++mt)                                             \
      _Pragma("unroll")                                                        \
      for (int bt = 0; bt < 2; ++bt)                                           \
        acc[mt][bt] = __builtin_amdgcn_mfma_f32_32x32x16_f16(                  \
            AH[mt], bh[bt], acc[mt][bt], 0, 0, 0);                             \
    _Pragma("unroll")                                                          \
    for (int mt = 0; mt < 4; ++mt)                                             \
      _Pragma("unroll")                                                        \
      for (int bt = 0; bt < 2; ++bt)                                           \
        acc[mt][bt] = __builtin_amdgcn_mfma_f32_32x32x16_f16(                  \
            AH[mt], bl[bt], acc[mt][bt], 0, 0, 0);                             \
    _Pragma("unroll")                                                          \
    for (int mt = 0; mt < 4; ++mt)                                             \
      _Pragma("unroll")                                                        \
      for (int bt = 0; bt < 2; ++bt)                                           \
        acc[mt][bt] = __builtin_amdgcn_mfma_f32_32x32x16_f16(                  \
            AL[mt], bh[bt], acc[mt][bt], 0, 0, 0);                             \
    __builtin_amdgcn_s_setprio(0);                                             \
  }

  // ---- prologue ----
  half8 ahA[4], alA[4], ahB[4], alB[4];
#pragma unroll
  for (int mt = 0; mt < 4; ++mt) {
    ahA[mt] = gWh[l5 * 256 + hidb + mt * 32];   // chunks of stage 0
    alA[mt] = gWl[l5 * 256 + hidb + mt * 32];
  }
  float4 x00 = *(const float4*)(xrow + 0);
  float4 x01 = *(const float4*)(xrow + 4);
  __syncthreads();  // sLbl/sB1/sW2 ready

  SPLIT_STORE(0, x00, x01, 0)
  float4 xa0 = *(const float4*)(xrow + 16);   // X(1)
  float4 xa1 = *(const float4*)(xrow + 20);
  float4 xb0 = *(const float4*)(xrow + 32);   // X(2)
  float4 xb1 = *(const float4*)(xrow + 36);
  LGKM0_BARRIER();

  // ---- main loop: 48 K16 stages, unrolled x2 (A/B frag sets, xa/xb ping-pong) --
  for (int ss = 0; ss < 24; ++ss) {
    // ===== even stage S = 2ss: consume frag set A, X from xa, read sB[0] =====
    {
      const int S = 2 * ss;
      {  // issue W(S+1) -> set B (regs free since stage S-1)
        const int cc = (S + 1) * 2 + l5;
#pragma unroll
        for (int mt = 0; mt < 4; ++mt) {
          ahB[mt] = gWh[(size_t)cc * 256 + hidb + mt * 32];
          alB[mt] = gWl[(size_t)cc * 256 + hidb + mt * 32];
        }
      }
      half8 bh[2], bl[2];
#pragma unroll
      for (int bt = 0; bt < 2; ++bt) {
        bh[bt] = *(const half8*)&sB[0][0][l5][pg * 64 + bt * 32 + ln][0];
        bl[bt] = *(const half8*)&sB[0][1][l5][pg * 64 + bt * 32 + ln][0];
      }
      MFMA_CLUSTER(ahA, alA)
      SPLIT_STORE(1, xa0, xa1, S + 1)  // X(S+1) -> sB[1]
      {
        const int s3 = (S + 3 > 47) ? 47 : S + 3;
        xa0 = *(const float4*)(xrow + s3 * 16);
        xa1 = *(const float4*)(xrow + s3 * 16 + 4);
      }
      LGKM0_BARRIER();
    }
    // ===== odd stage S = 2ss+1: consume frag set B, X from xb, read sB[1] =====
    {
      const int S = 2 * ss + 1;
      if (S < 47) {  // issue W(S+1) -> set A
        const int cc = (S + 1) * 2 + l5;
#pragma unroll
        for (int mt = 0; mt < 4; ++mt) {
          ahA[mt] = gWh[(size_t)cc * 256 + hidb + mt * 32];
          alA[mt] = gWl[(size_t)cc * 256 + hidb + mt * 32];
        }
      }
      half8 bh[2], bl[2];
#pragma unroll
      for (int bt = 0; bt < 2; ++bt) {
        bh[bt] = *(const half8*)&sB[1][0][l5][pg * 64 + bt * 32 + ln][0];
        bl[bt] = *(const half8*)&sB[1][1][l5][pg * 64 + bt * 32 + ln][0];
      }
      MFMA_CLUSTER(ahB, alB)
      if (S < 47) {
        SPLIT_STORE(0, xb0, xb1, S + 1)  // X(S+1) -> sB[0]
        const int s3 = (S + 3 > 47) ? 47 : S + 3;
        xb0 = *(const float4*)(xrow + s3 * 16);
        xb1 = *(const float4*)(xrow + s3 * 16 + 4);
      }
      LGKM0_BARRIER();
    }
  }
#undef SPLIT_STORE
#undef MFMA_CLUSTER

  // ---- epilogue ----
  sq += __shfl_xor(sq, 1);
  dt += __shfl_xor(dt, 1);
  if (h2 == 0) sLsc[r] = dt / fmaxf(sqrtf(sq), 1e-12f);

  float vsb[2] = {0.f, 0.f};
#pragma unroll
  for (int mt = 0; mt < 4; ++mt) {
#pragma unroll
    for (int rq = 0; rq < 4; ++rq) {
      const int hb = hh * 128 + mt * 32 + rq * 8 + l5 * 4;
      const float4 b1v = *(const float4*)&sB1[hb];
      const float4 w2v = *(const float4*)&sW2[hb];
#pragma unroll
      for (int j = 0; j < 4; ++j) {
        float h0 = acc[mt][0][rq * 4 + j] * INV_S + (&b1v.x)[j];
        float h1 = acc[mt][1][rq * 4 + j] * INV_S + (&b1v.x)[j];
        vsb[0] += fmaxf(h0, 0.f) * (&w2v.x)[j];
        vsb[1] += fmaxf(h1, 0.f) * (&w2v.x)[j];
      }
    }
  }
  vsb[0] += __shfl_xor(vsb[0], 32);
  vsb[1] += __shfl_xor(vsb[1], 32);
  if (l < 32) {
    sVs[hh][pg * 64 + l]      = vsb[0];
    sVs[hh][pg * 64 + 32 + l] = vsb[1];
  }
  __syncthreads();

  if (t < 128) {
    float vst = sVs[0][t] + sVs[1][t] + b2[0];
    scores[pb + t] = 0.4f * vst + 0.6f * sLsc[t];
  }
}

// ---------------- Kernel C: per-batch exact top-K, cached wave-max tournament --
__global__ __launch_bounds__(256) void topk3_kernel(
    const float* __restrict__ scores, int* __restrict__ out_idx, int K) {
  int b = blockIdx.x;
  int t = threadIdx.x;
  int wv = t >> 6, l = t & 63;
  __shared__ ull swm[4];

  ull keys[16];
#pragma unroll
  for (int j = 0; j < 16; ++j) {
    int i = (j << 8) + t;  // coalesced
    float s = scores[(b << 12) + i];
    unsigned u = __float_as_uint(s);
    u = (u & 0x80000000u) ? ~u : (u | 0x80000000u);
    keys[j] = ((ull)u << 32) | (unsigned)(4095 - i);  // tie -> lower index wins
  }
  ull cur = 0;
#pragma unroll
  for (int j = 0; j < 16; ++j) cur = keys[j] > cur ? keys[j] : cur;

  {  // initial per-wave reduce
    ull wb = cur;
#pragma unroll
    for (int off = 1; off < 64; off <<= 1) {
      ull o = __shfl_xor(wb, off);
      wb = o > wb ? o : wb;
    }
    if (l == 0) swm[wv] = wb;
  }
  __syncthreads();

  for (int sel = 0; sel < K; ++sel) {
    ull m0 = swm[0] > swm[1] ? swm[0] : swm[1];
    ull m1 = swm[2] > swm[3] ? swm[2] : swm[3];
    ull best = m0 > m1 ? m0 : m1;
    if (t == 0) out_idx[b * K + sel] = 4095 - (int)(unsigned)(best & 0xFFFFFFFFull);
    if (swm[wv] == best) {  // wave-uniform: only the owning wave re-reduces
      if (cur == best) {    // owning thread drops the winner, rescans its 16
        cur = 0;
#pragma unroll
        for (int j = 0; j < 16; ++j)
          cur = (keys[j] < best && keys[j] > cur) ? keys[j] : cur;
      }
      ull wb = cur;
#pragma unroll
      for (int off = 1; off < 64; off <<= 1) {
        ull o = __shfl_xor(wb, off);
        wb = o > wb ? o : wb;
      }
      if (l == 0) swm[wv] = wb;
    }
    __syncthreads();
  }
}

// ---------------- Kernel D: gather + float-encode indices ----------------
__global__ __launch_bounds__(192) void gather_kernel(
    const float* __restrict__ feats, const int* __restrict__ idx,
    float* __restrict__ out_feats, float* __restrict__ out_idx_f, int K) {
  int i = blockIdx.x;
  int b = blockIdx.y;
  int id = idx[b * K + i];
  const float4* src = (const float4*)&feats[((size_t)b * N_ + id) * D_];
  float4* dst = (float4*)&out_feats[((size_t)b * K + i) * D_];
  dst[threadIdx.x] = src[threadIdx.x];
  if (threadIdx.x == 0) out_idx_f[b * K + i] = (float)id;
}

extern "C" void kernel_launch(void* const* d_in, const int* in_sizes, int n_in,
                              void* d_out, int out_size, void* d_ws, size_t ws_size,
                              hipStream_t stream) {
  const float* feats = (const float*)d_in[0];
  const float* lc    = (const float*)d_in[1];
  const float* W1    = (const float*)d_in[2];
  const float* b1    = (const float*)d_in[3];
  const float* W2    = (const float*)d_in[4];
  const float* b2    = (const float*)d_in[5];
  const float* Wp    = (const float*)d_in[6];
  const float* bp    = (const float*)d_in[7];
  int K = out_size / (B_ * (D_ + 1));  // 192

  float* ws_f    = (float*)d_ws;
  float* lbl_n   = ws_f;                              // 32*768
  float* scoresv = ws_f + B_ * D_;                    // 32*4096
  int*   topidx  = (int*)(ws_f + B_ * D_ + B_ * N_);  // 32*192
  size_t off = (size_t)B_ * D_ + (size_t)B_ * N_ + B_ * 256;
  off = (off + 3) & ~(size_t)3;
  _Float16* whi = (_Float16*)(ws_f + off);            // 96*256*8 halves
  _Float16* wlo = whi + (size_t)96 * 256 * 8;

  float* out_f     = (float*)d_out;
  float* out_idx_f = out_f + (size_t)B_ * K * D_;

  prep_kernel<<<128, 256, 0, stream>>>(W1, whi, wlo, lc, Wp, bp, lbl_n);
  score8_kernel<<<(B_ * N_) / 128, 256, 0, stream>>>(feats, whi, wlo, b1, W2, b2,
                                                     lbl_n, scoresv);
  topk3_kernel<<<B_, 256, 0, stream>>>(scoresv, topidx, K);
  gather_kernel<<<dim3(K, B_), 192, 0, stream>>>(feats, topidx, out_f, out_idx_f, K);
}